// Round 2
// baseline (55.269 us; speedup 1.0000x reference)
//
#include <hip/hip_runtime.h>
#include <hip/hip_bf16.h>
#include <math.h>

// Scalar damped-Newton minimization of a degree-6 polynomial (7 coeffs).
// Same fixed point & termination as the JAX reference:
//   while (g2 > 1e-12 && it < 100):
//     g = p'(x); h = p''(x)
//     step = h > 0 ? g/h : 0.1*g
//     x -= step; g2 = p'(x)^2; it++
//
// Latency-optimized: the loop is a pure dependent chain, so we
//  (1) carry g across iterations (bit-exact: ref recomputes p'(x) at the
//      same x it just evaluated),
//  (2) evaluate p' and p'' with Estrin (x^2/x^4 fma tree, ~16-cyc chain
//      instead of ~44 for the power series),
//  (3) use raw v_rcp_f32 instead of the precise-divide sequence — rcp error
//      only scales the Newton step, the fixed point p'(x)=0 is unchanged.

#define MAX_ITER 100
#define GRAD_SQ_TOL 1e-12f

__global__ void __launch_bounds__(64)
polymin_kernel(const float* __restrict__ poly,
               const float* __restrict__ x_init,
               float* __restrict__ out) {
    // All 64 lanes compute redundantly (no divergence); lane 0 stores.
    float c0 = poly[0], c1 = poly[1], c2 = poly[2], c3 = poly[3],
          c4 = poly[4], c5 = poly[5], c6 = poly[6];
    (void)c0;

    // p' coefficients (lowest-degree-first)
    const float d10 = c1;
    const float d11 = 2.0f * c2;
    const float d12 = 3.0f * c3;
    const float d13 = 4.0f * c4;
    const float d14 = 5.0f * c5;
    const float d15 = 6.0f * c6;
    // p'' coefficients
    const float d20 = d11;          // 2*c2
    const float d21 = 2.0f * d12;   // 6*c3
    const float d22 = 3.0f * d13;   // 12*c4
    const float d23 = 4.0f * d14;   // 20*c5
    const float d24 = 5.0f * d15;   // 30*c6

    float x = x_init[0];

    // Estrin: p'(x) = (d10 + d11 x) + x2 (d12 + d13 x) + x4 (d14 + d15 x)
    float x2 = x * x;
    float x4 = x2 * x2;
    float g = fmaf(x4, fmaf(x, d15, d14),
              fmaf(x2, fmaf(x, d13, d12),
                        fmaf(x, d11, d10)));

    float g2 = INFINITY;
    int it = 0;

    while (g2 > GRAD_SQ_TOL && it < MAX_ITER) {
        // p''(x) = (d20 + d21 x) + x2 (d22 + d23 x) + x4 d24
        float h = fmaf(x4, d24,
                  fmaf(x2, fmaf(x, d23, d22),
                            fmaf(x, d21, d20)));
        float r = __builtin_amdgcn_rcpf(h);        // v_rcp_f32, ~1 ulp
        float step = (h > 0.0f) ? (g * r) : (0.1f * g);
        x = x - step;

        x2 = x * x;
        x4 = x2 * x2;
        g = fmaf(x4, fmaf(x, d15, d14),
            fmaf(x2, fmaf(x, d13, d12),
                      fmaf(x, d11, d10)));
        g2 = g * g;
        ++it;
    }

    if (threadIdx.x == 0) out[0] = x;
}

extern "C" void kernel_launch(void* const* d_in, const int* in_sizes, int n_in,
                              void* d_out, int out_size, void* d_ws, size_t ws_size,
                              hipStream_t stream) {
    const float* poly   = (const float*)d_in[0];  // 7 coeffs, lowest-degree-first
    const float* x_init = (const float*)d_in[1];  // scalar
    float* out = (float*)d_out;                   // scalar x_min

    polymin_kernel<<<1, 64, 0, stream>>>(poly, x_init, out);
}